// Round 1
// baseline (3007.328 us; speedup 1.0000x reference)
//
#include <hip/hip_runtime.h>
#include <math.h>

#define D 128

// ---------------- degree / normalization ----------------

__global__ __launch_bounds__(256) void zero_deg_kernel(int* __restrict__ deg, int n) {
  int i = blockIdx.x * 256 + threadIdx.x;
  if (i < n) deg[i] = 0;
}

__global__ __launch_bounds__(256) void count_deg_kernel(const int* __restrict__ dst, int E,
                                                        int* __restrict__ deg) {
  int e = blockIdx.x * 256 + threadIdx.x;
  if (e < E) atomicAdd(&deg[dst[e]], 1);
}

__global__ __launch_bounds__(256) void dinv_kernel(const int* __restrict__ deg,
                                                   float* __restrict__ dinv, int n) {
  int i = blockIdx.x * 256 + threadIdx.x;
  if (i < n) dinv[i] = 1.0f / sqrtf((float)(deg[i] + 1));  // +1: self-loop
}

// ---------------- GEMM: H[n,128] = X[n,128] @ W^T  (W row-major [128,128]) ----------------
// k-split halves keep LDS at ~50 KB -> 3 blocks/CU (12 waves/CU).
// Thread (ty,tx) of 256: rows {ty, ty+8, ty+16, ty+24} of a 32-row tile, cols tx*4..tx*4+3.

#define WS_PAD 132  // 128+4: breaks the stride-128 all-same-bank pattern, keeps 16B align

__global__ __launch_bounds__(256) void gemm128_kernel(const float* __restrict__ X,
                                                      const float* __restrict__ W,
                                                      float* __restrict__ H, int n) {
  __shared__ float Ws[64 * WS_PAD];   // transposed half: Ws[k-kt][j] = W[j][k]
  __shared__ float Xs[32 * 128];
  const int tid = threadIdx.x;
  const int tx = tid & 31;
  const int ty = tid >> 5;
  const int ntiles = (n + 31) >> 5;

  for (int tile = blockIdx.x; tile < ntiles; tile += gridDim.x) {
    const int row0 = tile << 5;
    const int rows_here = min(32, n - row0);
    __syncthreads();  // previous iteration's reads of Xs/Ws done
    // load X tile (32 rows x 128) coalesced as float4
    {
      const float4* Xg = (const float4*)(X + (size_t)row0 * D);
      int tmax = rows_here * 32;  // float4s
      for (int t = tid; t < tmax; t += 256) ((float4*)Xs)[t] = Xg[t];
    }
    float acc[4][4] = {{0.f}};
    #pragma unroll
    for (int kt = 0; kt < 128; kt += 64) {
      __syncthreads();  // prior compute done with Ws (and X load done for kt==0)
      // load+transpose W[:, kt:kt+64): 2048 float4s
      for (int t = tid; t < 2048; t += 256) {
        int j  = t >> 4;                  // W row 0..127
        int k4 = (t & 15) << 2;           // 0..60 within half
        float4 w = ((const float4*)W)[j * 32 + (kt >> 2) + (t & 15)];
        Ws[(k4 + 0) * WS_PAD + j] = w.x;
        Ws[(k4 + 1) * WS_PAD + j] = w.y;
        Ws[(k4 + 2) * WS_PAD + j] = w.z;
        Ws[(k4 + 3) * WS_PAD + j] = w.w;
      }
      __syncthreads();
      #pragma unroll 4
      for (int k = 0; k < 64; ++k) {
        float4 w = *(const float4*)&Ws[k * WS_PAD + (tx << 2)];
        #pragma unroll
        for (int r = 0; r < 4; ++r) {
          float xv = Xs[(ty + 8 * r) * 128 + (kt + k)];
          acc[r][0] += xv * w.x;
          acc[r][1] += xv * w.y;
          acc[r][2] += xv * w.z;
          acc[r][3] += xv * w.w;
        }
      }
    }
    #pragma unroll
    for (int r = 0; r < 4; ++r) {
      int row = row0 + ty + 8 * r;
      if (row < n)
        ((float4*)(H + (size_t)row * D))[tx] =
            make_float4(acc[r][0], acc[r][1], acc[r][2], acc[r][3]);
    }
  }
}

// ---------------- agg init: bias + perturb + self-loop term ----------------
// agg[i][j] = b[j] + perturb[i][j] + dinv[i]^2 * H[i][j]

__global__ __launch_bounds__(256) void init_agg_kernel(const float* __restrict__ H,
                                                       const float* __restrict__ bias,
                                                       const float* __restrict__ perturb,
                                                       const float* __restrict__ dinv,
                                                       float* __restrict__ agg, int n) {
  int idx = blockIdx.x * 256 + threadIdx.x;  // float4 index
  int total = n * 32;
  if (idx >= total) return;
  int i  = idx >> 5;
  int j4 = (idx & 31) << 2;
  float s = dinv[i];
  s = s * s;
  float4 h = ((const float4*)H)[idx];
  float4 p = ((const float4*)perturb)[idx];
  float4 b = *(const float4*)&bias[j4];
  float4 o;
  o.x = b.x + p.x + s * h.x;
  o.y = b.y + p.y + s * h.y;
  o.z = b.z + p.z + s * h.z;
  o.w = b.w + p.w + s * h.w;
  ((float4*)agg)[idx] = o;
}

// ---------------- edge scatter: agg[dst] += dinv[src]*dinv[dst] * H[src] ----------------
// one wave (64 lanes) per edge; lane handles 2 consecutive floats (coalesced 512B row read)

__global__ __launch_bounds__(256) void scatter_kernel(const int* __restrict__ src,
                                                      const int* __restrict__ dst,
                                                      const float* __restrict__ dinv,
                                                      const float* __restrict__ H,
                                                      float* __restrict__ agg, int E) {
  int wid  = (blockIdx.x << 2) + (threadIdx.x >> 6);
  int lane = threadIdx.x & 63;
  if (wid >= E) return;
  int s = src[wid], d = dst[wid];
  float norm = dinv[s] * dinv[d];
  float2 h = ((const float2*)(H + (size_t)s * D))[lane];
  float* out = agg + (size_t)d * D + (lane << 1);
  atomicAdd(out,     norm * h.x);
  atomicAdd(out + 1, norm * h.y);
}

// ---------------- launch ----------------

extern "C" void kernel_launch(void* const* d_in, const int* in_sizes, int n_in,
                              void* d_out, int out_size, void* d_ws, size_t ws_size,
                              hipStream_t stream) {
  const float* x  = (const float*)d_in[0];
  const int*   ei = (const int*)d_in[1];
  const float* pf = (const float*)d_in[2];
  const float* pl = (const float*)d_in[3];
  const float* W1 = (const float*)d_in[4];
  const float* b1 = (const float*)d_in[5];
  const float* W2 = (const float*)d_in[6];
  const float* b2 = (const float*)d_in[7];
  float* out = (float*)d_out;

  const int n = in_sizes[0] / D;
  const int E = in_sizes[1] / 2;
  const int* src = ei;      // edge_index[0]
  const int* dst = ei + E;  // edge_index[1]

  int*   deg  = (int*)d_ws;
  float* dinv = (float*)d_ws + n;
  float* A    = (float*)((char*)d_ws + (((size_t)2 * n * 4 + 255) & ~(size_t)255));  // N*D scratch

  const int nb_n = (n + 255) / 256;
  const int nb_e = (E + 255) / 256;
  const int nb_f4 = (n * 32 + 255) / 256;
  const int nb_sc = (E + 3) / 4;

  zero_deg_kernel<<<nb_n, 256, 0, stream>>>(deg, n);
  count_deg_kernel<<<nb_e, 256, 0, stream>>>(dst, E, deg);
  dinv_kernel<<<nb_n, 256, 0, stream>>>(deg, dinv, n);

  // layer 1: h1 = x@W1^T -> A ; agg1 -> out (used as scratch)
  gemm128_kernel<<<1024, 256, 0, stream>>>(x, W1, A, n);
  init_agg_kernel<<<nb_f4, 256, 0, stream>>>(A, b1, pf, dinv, out, n);
  scatter_kernel<<<nb_sc, 256, 0, stream>>>(src, dst, dinv, A, out, E);

  // layer 2: h2 = agg1@W2^T -> A ; agg2 -> out (final)
  gemm128_kernel<<<1024, 256, 0, stream>>>(out, W2, A, n);
  init_agg_kernel<<<nb_f4, 256, 0, stream>>>(A, b2, pl, dinv, out, n);
  scatter_kernel<<<nb_sc, 256, 0, stream>>>(src, dst, dinv, A, out, E);
}

// Round 2
// 743.760 us; speedup vs baseline: 4.0434x; 4.0434x over previous
//
#include <hip/hip_runtime.h>
#include <math.h>

#define D 128

// ---------------- degree / normalization ----------------

__global__ __launch_bounds__(256) void zero_deg_kernel(int* __restrict__ deg, int n) {
  int i = blockIdx.x * 256 + threadIdx.x;
  if (i < n) deg[i] = 0;
}

__global__ __launch_bounds__(256) void count_deg_kernel(const int* __restrict__ dst, int E,
                                                        int* __restrict__ deg) {
  int e = blockIdx.x * 256 + threadIdx.x;
  if (e < E) atomicAdd(&deg[dst[e]], 1);
}

__global__ __launch_bounds__(256) void dinv_kernel(const int* __restrict__ deg,
                                                   float* __restrict__ dinv, int n) {
  int i = blockIdx.x * 256 + threadIdx.x;
  if (i < n) dinv[i] = 1.0f / sqrtf((float)(deg[i] + 1));  // +1: self-loop
}

// ---------------- exclusive prefix scan of deg -> ptr (3 kernels) ----------------

__global__ __launch_bounds__(256) void scan_blocksum_kernel(const int* __restrict__ deg, int n,
                                                            int* __restrict__ blockSums) {
  __shared__ int sm[256];
  int t = threadIdx.x;
  int i = blockIdx.x * 256 + t;
  sm[t] = (i < n) ? deg[i] : 0;
  __syncthreads();
  for (int off = 128; off > 0; off >>= 1) {
    if (t < off) sm[t] += sm[t + off];
    __syncthreads();
  }
  if (t == 0) blockSums[blockIdx.x] = sm[0];
}

// single block, 512 threads; nb <= 512
__global__ __launch_bounds__(512) void scan_top_kernel(int* __restrict__ blockSums, int nb) {
  __shared__ int sm[512];
  int t = threadIdx.x;
  int v = (t < nb) ? blockSums[t] : 0;
  sm[t] = v;
  __syncthreads();
  for (int off = 1; off < 512; off <<= 1) {
    int x = (t >= off) ? sm[t - off] : 0;
    __syncthreads();
    sm[t] += x;
    __syncthreads();
  }
  if (t < nb) blockSums[t] = sm[t] - v;  // exclusive
}

__global__ __launch_bounds__(256) void scan_write_kernel(const int* __restrict__ deg, int n,
                                                         const int* __restrict__ blockSums,
                                                         int* __restrict__ ptr) {
  __shared__ int sm[256];
  int t = threadIdx.x;
  int i = blockIdx.x * 256 + t;
  int v = (i < n) ? deg[i] : 0;
  sm[t] = v;
  __syncthreads();
  for (int off = 1; off < 256; off <<= 1) {
    int x = (t >= off) ? sm[t - off] : 0;
    __syncthreads();
    sm[t] += x;
    __syncthreads();
  }
  if (i < n) ptr[i] = blockSums[blockIdx.x] + sm[t] - v;  // exclusive prefix
}

// ---------------- CSR fill (counting sort by dst) ----------------
// After this, ptr[i] == row_end(i) == original exclusive_prefix[i+1].

__global__ __launch_bounds__(256) void fill_csr_kernel(const int* __restrict__ src,
                                                       const int* __restrict__ dst,
                                                       int* __restrict__ ptr,
                                                       int* __restrict__ csr, int E) {
  int e = blockIdx.x * 256 + threadIdx.x;
  if (e < E) {
    int d = dst[e];
    int pos = atomicAdd(&ptr[d], 1);
    csr[pos] = src[e];
  }
}

// ---------------- GEMM: Hs[n,128] = dinv[i] * (X[n,128] @ W^T) ----------------

#define WS_PAD 132  // 128+4: breaks stride-128 bank pattern, keeps 16B align

__global__ __launch_bounds__(256) void gemm128_kernel(const float* __restrict__ X,
                                                      const float* __restrict__ W,
                                                      const float* __restrict__ dinv,
                                                      float* __restrict__ H, int n) {
  __shared__ float Ws[64 * WS_PAD];   // transposed half: Ws[k-kt][j] = W[j][k]
  __shared__ float Xs[32 * 128];
  const int tid = threadIdx.x;
  const int tx = tid & 31;
  const int ty = tid >> 5;
  const int ntiles = (n + 31) >> 5;

  for (int tile = blockIdx.x; tile < ntiles; tile += gridDim.x) {
    const int row0 = tile << 5;
    const int rows_here = min(32, n - row0);
    __syncthreads();
    {
      const float4* Xg = (const float4*)(X + (size_t)row0 * D);
      int tmax = rows_here * 32;
      for (int t = tid; t < tmax; t += 256) ((float4*)Xs)[t] = Xg[t];
    }
    float acc[4][4] = {{0.f}};
    #pragma unroll
    for (int kt = 0; kt < 128; kt += 64) {
      __syncthreads();
      for (int t = tid; t < 2048; t += 256) {
        int j  = t >> 4;
        int k4 = (t & 15) << 2;
        float4 w = ((const float4*)W)[j * 32 + (kt >> 2) + (t & 15)];
        Ws[(k4 + 0) * WS_PAD + j] = w.x;
        Ws[(k4 + 1) * WS_PAD + j] = w.y;
        Ws[(k4 + 2) * WS_PAD + j] = w.z;
        Ws[(k4 + 3) * WS_PAD + j] = w.w;
      }
      __syncthreads();
      #pragma unroll 4
      for (int k = 0; k < 64; ++k) {
        float4 w = *(const float4*)&Ws[k * WS_PAD + (tx << 2)];
        #pragma unroll
        for (int r = 0; r < 4; ++r) {
          float xv = Xs[(ty + 8 * r) * 128 + (kt + k)];
          acc[r][0] += xv * w.x;
          acc[r][1] += xv * w.y;
          acc[r][2] += xv * w.z;
          acc[r][3] += xv * w.w;
        }
      }
    }
    #pragma unroll
    for (int r = 0; r < 4; ++r) {
      int row = row0 + ty + 8 * r;
      if (row < n) {
        float s = dinv[row];
        ((float4*)(H + (size_t)row * D))[tx] =
            make_float4(s * acc[r][0], s * acc[r][1], s * acc[r][2], s * acc[r][3]);
      }
    }
  }
}

// ---------------- fused gather-aggregate ----------------
// out[i] = b + perturb[i] + dinv[i] * ( Hs[i] + sum_{e in in(i)} Hs[src_e] )
// one wave per node; lane handles float2 (full 512B row per wave, coalesced)

__global__ __launch_bounds__(256) void gather_kernel(const int* __restrict__ csr,
                                                     const int* __restrict__ rend,
                                                     const float* __restrict__ dinv,
                                                     const float* __restrict__ Hs,
                                                     const float* __restrict__ bias,
                                                     const float* __restrict__ perturb,
                                                     float* __restrict__ out, int n) {
  int i = (blockIdx.x << 2) + (threadIdx.x >> 6);
  if (i >= n) return;
  int lane = threadIdx.x & 63;
  int start = (i == 0) ? 0 : rend[i - 1];
  int end = rend[i];

  float2 acc = ((const float2*)(Hs + (size_t)i * D))[lane];  // self-loop term
  int e = start;
  for (; e + 4 <= end; e += 4) {
    int s0 = csr[e], s1 = csr[e + 1], s2 = csr[e + 2], s3 = csr[e + 3];
    float2 h0 = ((const float2*)(Hs + (size_t)s0 * D))[lane];
    float2 h1 = ((const float2*)(Hs + (size_t)s1 * D))[lane];
    float2 h2 = ((const float2*)(Hs + (size_t)s2 * D))[lane];
    float2 h3 = ((const float2*)(Hs + (size_t)s3 * D))[lane];
    acc.x += (h0.x + h1.x) + (h2.x + h3.x);
    acc.y += (h0.y + h1.y) + (h2.y + h3.y);
  }
  for (; e < end; ++e) {
    int s = csr[e];
    float2 h = ((const float2*)(Hs + (size_t)s * D))[lane];
    acc.x += h.x;
    acc.y += h.y;
  }
  float di = dinv[i];
  float2 p = ((const float2*)(perturb + (size_t)i * D))[lane];
  float2 b = ((const float2*)bias)[lane];
  float2 o;
  o.x = b.x + p.x + di * acc.x;
  o.y = b.y + p.y + di * acc.y;
  ((float2*)(out + (size_t)i * D))[lane] = o;
}

// ---------------- launch ----------------

extern "C" void kernel_launch(void* const* d_in, const int* in_sizes, int n_in,
                              void* d_out, int out_size, void* d_ws, size_t ws_size,
                              hipStream_t stream) {
  const float* x  = (const float*)d_in[0];
  const int*   ei = (const int*)d_in[1];
  const float* pf = (const float*)d_in[2];
  const float* pl = (const float*)d_in[3];
  const float* W1 = (const float*)d_in[4];
  const float* b1 = (const float*)d_in[5];
  const float* W2 = (const float*)d_in[6];
  const float* b2 = (const float*)d_in[7];
  float* out = (float*)d_out;

  const int n = in_sizes[0] / D;
  const int E = in_sizes[1] / 2;
  const int* src = ei;      // edge_index[0]
  const int* dst = ei + E;  // edge_index[1]

  // workspace layout
  int*   deg       = (int*)d_ws;                 // [n]
  float* dinv      = (float*)d_ws + n;           // [n]
  int*   ptr       = (int*)d_ws + 2 * n;         // [n] (becomes row_end after fill)
  int*   blockSums = (int*)d_ws + 3 * n;         // [<=512]
  int*   csr       = (int*)d_ws + 3 * n + 512;   // [E]
  float* A = (float*)((char*)d_ws + (((size_t)(3 * n + 512 + E) * 4 + 255) & ~(size_t)255));

  const int nb_n = (n + 255) / 256;
  const int nb_e = (E + 255) / 256;
  const int nb_g = (n + 3) / 4;

  zero_deg_kernel<<<nb_n, 256, 0, stream>>>(deg, n);
  count_deg_kernel<<<nb_e, 256, 0, stream>>>(dst, E, deg);
  dinv_kernel<<<nb_n, 256, 0, stream>>>(deg, dinv, n);

  scan_blocksum_kernel<<<nb_n, 256, 0, stream>>>(deg, n, blockSums);
  scan_top_kernel<<<1, 512, 0, stream>>>(blockSums, nb_n);
  scan_write_kernel<<<nb_n, 256, 0, stream>>>(deg, n, blockSums, ptr);
  fill_csr_kernel<<<nb_e, 256, 0, stream>>>(src, dst, ptr, csr, E);

  // layer 1: Hs1 = dinv*(x@W1^T) -> A ; gather -> out
  gemm128_kernel<<<1024, 256, 0, stream>>>(x, W1, dinv, A, n);
  gather_kernel<<<nb_g, 256, 0, stream>>>(csr, ptr, dinv, A, b1, pf, out, n);

  // layer 2: Hs2 = dinv*(out@W2^T) -> A ; gather -> out
  gemm128_kernel<<<1024, 256, 0, stream>>>(out, W2, dinv, A, n);
  gather_kernel<<<nb_g, 256, 0, stream>>>(csr, ptr, dinv, A, b2, pl, out, n);
}

// Round 3
// 620.593 us; speedup vs baseline: 4.8459x; 1.1985x over previous
//
#include <hip/hip_runtime.h>
#include <math.h>

#define D 128
#define WS_PAD 132  // 128+4: breaks stride-128 bank pattern, keeps 16B align

__device__ __forceinline__ unsigned short f2bf(float f) {
  unsigned u = __float_as_uint(f);
  u += 0x7FFFu + ((u >> 16) & 1u);  // round-to-nearest-even
  return (unsigned short)(u >> 16);
}

// ---------------- degree count ----------------

__global__ __launch_bounds__(256) void count_deg_kernel(const int* __restrict__ dst, int E,
                                                        int* __restrict__ deg) {
  int e = blockIdx.x * 256 + threadIdx.x;
  if (e < E) atomicAdd(&deg[dst[e]], 1);
}

// ---------------- exclusive prefix scan of deg -> ptr ----------------

__global__ __launch_bounds__(256) void scan_blocksum_kernel(const int* __restrict__ deg, int n,
                                                            int* __restrict__ blockSums) {
  __shared__ int sm[256];
  int t = threadIdx.x;
  int i = blockIdx.x * 256 + t;
  sm[t] = (i < n) ? deg[i] : 0;
  __syncthreads();
  for (int off = 128; off > 0; off >>= 1) {
    if (t < off) sm[t] += sm[t + off];
    __syncthreads();
  }
  if (t == 0) blockSums[blockIdx.x] = sm[0];
}

// single block, 512 threads; nb <= 512
__global__ __launch_bounds__(512) void scan_top_kernel(int* __restrict__ blockSums, int nb) {
  __shared__ int sm[512];
  int t = threadIdx.x;
  int v = (t < nb) ? blockSums[t] : 0;
  sm[t] = v;
  __syncthreads();
  for (int off = 1; off < 512; off <<= 1) {
    int x = (t >= off) ? sm[t - off] : 0;
    __syncthreads();
    sm[t] += x;
    __syncthreads();
  }
  if (t < nb) blockSums[t] = sm[t] - v;  // exclusive
}

// also computes dinv (fused to save a launch)
__global__ __launch_bounds__(256) void scan_write_kernel(const int* __restrict__ deg, int n,
                                                         const int* __restrict__ blockSums,
                                                         int* __restrict__ ptr,
                                                         float* __restrict__ dinv) {
  __shared__ int sm[256];
  int t = threadIdx.x;
  int i = blockIdx.x * 256 + t;
  int v = (i < n) ? deg[i] : 0;
  sm[t] = v;
  __syncthreads();
  for (int off = 1; off < 256; off <<= 1) {
    int x = (t >= off) ? sm[t - off] : 0;
    __syncthreads();
    sm[t] += x;
    __syncthreads();
  }
  if (i < n) {
    ptr[i] = blockSums[blockIdx.x] + sm[t] - v;  // exclusive prefix
    dinv[i] = 1.0f / sqrtf((float)(v + 1));      // +1: self-loop
  }
}

// ---------------- shared GEMM body: H[n,128](bf16) = dinv[i] * (X @ W^T) ----------------

__device__ __forceinline__ void gemm_body(const float* __restrict__ X,
                                          const float* __restrict__ W,
                                          const float* __restrict__ dinv,
                                          unsigned short* __restrict__ H, int n,
                                          int bid, int nblocks,
                                          float* __restrict__ Ws, float* __restrict__ Xs) {
  const int tid = threadIdx.x;
  const int tx = tid & 31;
  const int ty = tid >> 5;
  const int ntiles = (n + 31) >> 5;

  for (int tile = bid; tile < ntiles; tile += nblocks) {
    const int row0 = tile << 5;
    const int rows_here = min(32, n - row0);
    __syncthreads();
    {
      const float4* Xg = (const float4*)(X + (size_t)row0 * D);
      int tmax = rows_here * 32;
      for (int t = tid; t < tmax; t += 256) ((float4*)Xs)[t] = Xg[t];
    }
    float acc[4][4] = {{0.f}};
    #pragma unroll
    for (int kt = 0; kt < 128; kt += 64) {
      __syncthreads();
      for (int t = tid; t < 2048; t += 256) {
        int j  = t >> 4;
        int k4 = (t & 15) << 2;
        float4 w = ((const float4*)W)[j * 32 + (kt >> 2) + (t & 15)];
        Ws[(k4 + 0) * WS_PAD + j] = w.x;
        Ws[(k4 + 1) * WS_PAD + j] = w.y;
        Ws[(k4 + 2) * WS_PAD + j] = w.z;
        Ws[(k4 + 3) * WS_PAD + j] = w.w;
      }
      __syncthreads();
      #pragma unroll 4
      for (int k = 0; k < 64; ++k) {
        float4 w = *(const float4*)&Ws[k * WS_PAD + (tx << 2)];
        #pragma unroll
        for (int r = 0; r < 4; ++r) {
          float xv = Xs[(ty + 8 * r) * 128 + (kt + k)];
          acc[r][0] += xv * w.x;
          acc[r][1] += xv * w.y;
          acc[r][2] += xv * w.z;
          acc[r][3] += xv * w.w;
        }
      }
    }
    #pragma unroll
    for (int r = 0; r < 4; ++r) {
      int row = row0 + ty + 8 * r;
      if (row < n) {
        float s = dinv[row];
        unsigned h0 = f2bf(s * acc[r][0]);
        unsigned h1 = f2bf(s * acc[r][1]);
        unsigned h2 = f2bf(s * acc[r][2]);
        unsigned h3 = f2bf(s * acc[r][3]);
        ((uint2*)(H + (size_t)row * D))[tx] = make_uint2(h0 | (h1 << 16), h2 | (h3 << 16));
      }
    }
  }
}

// ---------------- fused: CSR fill (atomic-latency-bound) || GEMM1 (VALU-bound) ----------------
// Block-interleaved partition: (blockIdx&7)<2 -> fill (512 of 2048 blocks); else GEMM (1536).
// Interleaving keeps ~25% of resident blocks on fill so its atomic throughput is sustained
// while GEMM soaks up the otherwise-idle VALU cycles.

#define FUSED_GRID 2048

__global__ __launch_bounds__(256) void fused_fill_gemm_kernel(
    const int* __restrict__ src, const int* __restrict__ dst,
    int* __restrict__ ptr, int* __restrict__ csr, int E,
    const float* __restrict__ X, const float* __restrict__ W,
    const float* __restrict__ dinv, unsigned short* __restrict__ H, int n) {
  __shared__ float Ws[64 * WS_PAD];
  __shared__ float Xs[32 * 128];
  int sub = blockIdx.x & 7;
  if (sub < 2) {
    // fill: 512 virtual blocks
    int fb = (blockIdx.x >> 3) * 2 + sub;
    int stride = 512 * 256;
    for (int e = fb * 256 + threadIdx.x; e < E; e += stride) {
      int d = dst[e];
      int pos = atomicAdd(&ptr[d], 1);
      csr[pos] = src[e];
    }
  } else {
    // gemm: 1536 virtual blocks
    int gb = (blockIdx.x >> 3) * 6 + (sub - 2);
    gemm_body(X, W, dinv, H, n, gb, 1536, Ws, Xs);
  }
}

__global__ __launch_bounds__(256) void gemm128_kernel(const float* __restrict__ X,
                                                      const float* __restrict__ W,
                                                      const float* __restrict__ dinv,
                                                      unsigned short* __restrict__ H, int n) {
  __shared__ float Ws[64 * WS_PAD];
  __shared__ float Xs[32 * 128];
  gemm_body(X, W, dinv, H, n, blockIdx.x, gridDim.x, Ws, Xs);
}

// ---------------- fused gather-aggregate (bf16 Hs rows, 256B each) ----------------
// out[i] = b + perturb[i] + dinv[i] * ( Hs[i] + sum_{e in in(i)} Hs[src_e] )
// one wave per node; lane loads one uint = 2 bf16 (elements 2*lane, 2*lane+1)

__global__ __launch_bounds__(256) void gather_kernel(const int* __restrict__ csr,
                                                     const int* __restrict__ rend,
                                                     const float* __restrict__ dinv,
                                                     const unsigned* __restrict__ Hu,
                                                     const float* __restrict__ bias,
                                                     const float* __restrict__ perturb,
                                                     float* __restrict__ out, int n) {
  int i = (blockIdx.x << 2) + (threadIdx.x >> 6);
  if (i >= n) return;
  int lane = threadIdx.x & 63;
  int start = (i == 0) ? 0 : rend[i - 1];
  int end = rend[i];

  unsigned v = Hu[(size_t)i * 64 + lane];  // self-loop term
  float ax = __uint_as_float(v << 16);
  float ay = __uint_as_float(v & 0xFFFF0000u);

  int e = start;
  for (; e + 8 <= end; e += 8) {
    unsigned w0 = Hu[(size_t)csr[e + 0] * 64 + lane];
    unsigned w1 = Hu[(size_t)csr[e + 1] * 64 + lane];
    unsigned w2 = Hu[(size_t)csr[e + 2] * 64 + lane];
    unsigned w3 = Hu[(size_t)csr[e + 3] * 64 + lane];
    unsigned w4 = Hu[(size_t)csr[e + 4] * 64 + lane];
    unsigned w5 = Hu[(size_t)csr[e + 5] * 64 + lane];
    unsigned w6 = Hu[(size_t)csr[e + 6] * 64 + lane];
    unsigned w7 = Hu[(size_t)csr[e + 7] * 64 + lane];
    ax += __uint_as_float(w0 << 16) + __uint_as_float(w1 << 16) +
          __uint_as_float(w2 << 16) + __uint_as_float(w3 << 16) +
          __uint_as_float(w4 << 16) + __uint_as_float(w5 << 16) +
          __uint_as_float(w6 << 16) + __uint_as_float(w7 << 16);
    ay += __uint_as_float(w0 & 0xFFFF0000u) + __uint_as_float(w1 & 0xFFFF0000u) +
          __uint_as_float(w2 & 0xFFFF0000u) + __uint_as_float(w3 & 0xFFFF0000u) +
          __uint_as_float(w4 & 0xFFFF0000u) + __uint_as_float(w5 & 0xFFFF0000u) +
          __uint_as_float(w6 & 0xFFFF0000u) + __uint_as_float(w7 & 0xFFFF0000u);
  }
  for (; e < end; ++e) {
    unsigned w = Hu[(size_t)csr[e] * 64 + lane];
    ax += __uint_as_float(w << 16);
    ay += __uint_as_float(w & 0xFFFF0000u);
  }
  float di = dinv[i];
  float2 p = ((const float2*)(perturb + (size_t)i * D))[lane];
  float2 o;
  o.x = bias[2 * lane + 0] + p.x + di * ax;
  o.y = bias[2 * lane + 1] + p.y + di * ay;
  ((float2*)(out + (size_t)i * D))[lane] = o;
}

// ---------------- launch ----------------

extern "C" void kernel_launch(void* const* d_in, const int* in_sizes, int n_in,
                              void* d_out, int out_size, void* d_ws, size_t ws_size,
                              hipStream_t stream) {
  const float* x  = (const float*)d_in[0];
  const int*   ei = (const int*)d_in[1];
  const float* pf = (const float*)d_in[2];
  const float* pl = (const float*)d_in[3];
  const float* W1 = (const float*)d_in[4];
  const float* b1 = (const float*)d_in[5];
  const float* W2 = (const float*)d_in[6];
  const float* b2 = (const float*)d_in[7];
  float* out = (float*)d_out;

  const int n = in_sizes[0] / D;
  const int E = in_sizes[1] / 2;
  const int* src = ei;      // edge_index[0]
  const int* dst = ei + E;  // edge_index[1]

  // workspace layout
  int*   deg       = (int*)d_ws;                 // [n]
  float* dinv      = (float*)d_ws + n;           // [n]
  int*   ptr       = (int*)d_ws + 2 * n;         // [n] (becomes row_end after fill)
  int*   blockSums = (int*)d_ws + 3 * n;         // [<=512]
  int*   csr       = (int*)d_ws + 3 * n + 512;   // [E]
  unsigned short* A =
      (unsigned short*)((char*)d_ws + (((size_t)(3 * n + 512 + E) * 4 + 255) & ~(size_t)255));

  const int nb_n = (n + 255) / 256;
  const int nb_e = (E + 255) / 256;
  const int nb_g = (n + 3) / 4;

  hipMemsetAsync(deg, 0, (size_t)n * sizeof(int), stream);
  count_deg_kernel<<<nb_e, 256, 0, stream>>>(dst, E, deg);
  scan_blocksum_kernel<<<nb_n, 256, 0, stream>>>(deg, n, blockSums);
  scan_top_kernel<<<1, 512, 0, stream>>>(blockSums, nb_n);
  scan_write_kernel<<<nb_n, 256, 0, stream>>>(deg, n, blockSums, ptr, dinv);

  // layer 1: CSR fill || Hs1 = dinv*(x@W1^T) -> A ; then gather -> out
  fused_fill_gemm_kernel<<<FUSED_GRID, 256, 0, stream>>>(src, dst, ptr, csr, E, x, W1, dinv, A, n);
  gather_kernel<<<nb_g, 256, 0, stream>>>(csr, ptr, dinv, (const unsigned*)A, b1, pf, out, n);

  // layer 2: Hs2 = dinv*(out@W2^T) -> A ; gather -> out
  gemm128_kernel<<<1024, 256, 0, stream>>>(out, W2, dinv, A, n);
  gather_kernel<<<nb_g, 256, 0, stream>>>(csr, ptr, dinv, (const unsigned*)A, b2, pl, out, n);
}

// Round 4
// 584.094 us; speedup vs baseline: 5.1487x; 1.0625x over previous
//
#include <hip/hip_runtime.h>
#include <math.h>

#define D 128
#define WS_PAD 132  // 128+4: breaks stride-128 bank pattern, keeps 16B align

typedef short bf16x8 __attribute__((ext_vector_type(8)));  // 8 bf16 in 4 VGPRs
typedef float f32x4 __attribute__((ext_vector_type(4)));

__device__ __forceinline__ unsigned short f2bf(float f) {
  unsigned u = __float_as_uint(f);
  u += 0x7FFFu + ((u >> 16) & 1u);  // round-to-nearest-even
  return (unsigned short)(u >> 16);
}

// ---------------- degree count ----------------

__global__ __launch_bounds__(256) void count_deg_kernel(const int* __restrict__ dst, int E,
                                                        int* __restrict__ deg) {
  int e = blockIdx.x * 256 + threadIdx.x;
  if (e < E) atomicAdd(&deg[dst[e]], 1);
}

// ---------------- exclusive prefix scan of deg -> ptr ----------------

__global__ __launch_bounds__(256) void scan_blocksum_kernel(const int* __restrict__ deg, int n,
                                                            int* __restrict__ blockSums) {
  __shared__ int sm[256];
  int t = threadIdx.x;
  int i = blockIdx.x * 256 + t;
  sm[t] = (i < n) ? deg[i] : 0;
  __syncthreads();
  for (int off = 128; off > 0; off >>= 1) {
    if (t < off) sm[t] += sm[t + off];
    __syncthreads();
  }
  if (t == 0) blockSums[blockIdx.x] = sm[0];
}

// single block, 512 threads; nb <= 512
__global__ __launch_bounds__(512) void scan_top_kernel(int* __restrict__ blockSums, int nb) {
  __shared__ int sm[512];
  int t = threadIdx.x;
  int v = (t < nb) ? blockSums[t] : 0;
  sm[t] = v;
  __syncthreads();
  for (int off = 1; off < 512; off <<= 1) {
    int x = (t >= off) ? sm[t - off] : 0;
    __syncthreads();
    sm[t] += x;
    __syncthreads();
  }
  if (t < nb) blockSums[t] = sm[t] - v;  // exclusive
}

// also computes dinv (fused to save a launch)
__global__ __launch_bounds__(256) void scan_write_kernel(const int* __restrict__ deg, int n,
                                                         const int* __restrict__ blockSums,
                                                         int* __restrict__ ptr,
                                                         float* __restrict__ dinv) {
  __shared__ int sm[256];
  int t = threadIdx.x;
  int i = blockIdx.x * 256 + t;
  int v = (i < n) ? deg[i] : 0;
  sm[t] = v;
  __syncthreads();
  for (int off = 1; off < 256; off <<= 1) {
    int x = (t >= off) ? sm[t - off] : 0;
    __syncthreads();
    sm[t] += x;
    __syncthreads();
  }
  if (i < n) {
    ptr[i] = blockSums[blockIdx.x] + sm[t] - v;  // exclusive prefix
    dinv[i] = 1.0f / sqrtf((float)(v + 1));      // +1: self-loop
  }
}

// ---------------- shared GEMM body: H[n,128](bf16) = dinv[i] * (X @ W^T) ----------------

__device__ __forceinline__ void gemm_body(const float* __restrict__ X,
                                          const float* __restrict__ W,
                                          const float* __restrict__ dinv,
                                          unsigned short* __restrict__ H, int n,
                                          int bid, int nblocks,
                                          float* __restrict__ Ws, float* __restrict__ Xs) {
  const int tid = threadIdx.x;
  const int tx = tid & 31;
  const int ty = tid >> 5;
  const int ntiles = (n + 31) >> 5;

  for (int tile = bid; tile < ntiles; tile += nblocks) {
    const int row0 = tile << 5;
    const int rows_here = min(32, n - row0);
    __syncthreads();
    {
      const float4* Xg = (const float4*)(X + (size_t)row0 * D);
      int tmax = rows_here * 32;
      for (int t = tid; t < tmax; t += 256) ((float4*)Xs)[t] = Xg[t];
    }
    float acc[4][4] = {{0.f}};
    #pragma unroll
    for (int kt = 0; kt < 128; kt += 64) {
      __syncthreads();
      for (int t = tid; t < 2048; t += 256) {
        int j  = t >> 4;
        int k4 = (t & 15) << 2;
        float4 w = ((const float4*)W)[j * 32 + (kt >> 2) + (t & 15)];
        Ws[(k4 + 0) * WS_PAD + j] = w.x;
        Ws[(k4 + 1) * WS_PAD + j] = w.y;
        Ws[(k4 + 2) * WS_PAD + j] = w.z;
        Ws[(k4 + 3) * WS_PAD + j] = w.w;
      }
      __syncthreads();
      #pragma unroll 4
      for (int k = 0; k < 64; ++k) {
        float4 w = *(const float4*)&Ws[k * WS_PAD + (tx << 2)];
        #pragma unroll
        for (int r = 0; r < 4; ++r) {
          float xv = Xs[(ty + 8 * r) * 128 + (kt + k)];
          acc[r][0] += xv * w.x;
          acc[r][1] += xv * w.y;
          acc[r][2] += xv * w.z;
          acc[r][3] += xv * w.w;
        }
      }
    }
    #pragma unroll
    for (int r = 0; r < 4; ++r) {
      int row = row0 + ty + 8 * r;
      if (row < n) {
        float s = dinv[row];
        unsigned h0 = f2bf(s * acc[r][0]);
        unsigned h1 = f2bf(s * acc[r][1]);
        unsigned h2 = f2bf(s * acc[r][2]);
        unsigned h3 = f2bf(s * acc[r][3]);
        ((uint2*)(H + (size_t)row * D))[tx] = make_uint2(h0 | (h1 << 16), h2 | (h3 << 16));
      }
    }
  }
}

// ---------------- fused: CSR fill (atomic-latency-bound) || GEMM1 (VALU-bound) ----------------

#define FUSED_GRID 2048

__global__ __launch_bounds__(256) void fused_fill_gemm_kernel(
    const int* __restrict__ src, const int* __restrict__ dst,
    int* __restrict__ ptr, int* __restrict__ csr, int E,
    const float* __restrict__ X, const float* __restrict__ W,
    const float* __restrict__ dinv, unsigned short* __restrict__ H, int n) {
  __shared__ float Ws[64 * WS_PAD];
  __shared__ float Xs[32 * 128];
  int sub = blockIdx.x & 7;
  if (sub < 2) {
    int fb = (blockIdx.x >> 3) * 2 + sub;
    int stride = 512 * 256;
    for (int e = fb * 256 + threadIdx.x; e < E; e += stride) {
      int d = dst[e];
      int pos = atomicAdd(&ptr[d], 1);
      csr[pos] = src[e];
    }
  } else {
    int gb = (blockIdx.x >> 3) * 6 + (sub - 2);
    gemm_body(X, W, dinv, H, n, gb, 1536, Ws, Xs);
  }
}

__global__ __launch_bounds__(256) void gemm128_kernel(const float* __restrict__ X,
                                                      const float* __restrict__ W,
                                                      const float* __restrict__ dinv,
                                                      unsigned short* __restrict__ H, int n) {
  __shared__ float Ws[64 * WS_PAD];
  __shared__ float Xs[32 * 128];
  gemm_body(X, W, dinv, H, n, blockIdx.x, gridDim.x, Ws, Xs);
}

// ---------------- gather helper: accumulate row i of Hs (bf16) ----------------

__device__ __forceinline__ void gather_row(const int* __restrict__ csr,
                                           const int* __restrict__ rend,
                                           const unsigned* __restrict__ Hu,
                                           int i, int lane, float& ax, float& ay) {
  int start = (i == 0) ? 0 : rend[i - 1];
  int end = rend[i];
  unsigned v = Hu[(size_t)i * 64 + lane];  // self-loop term
  ax = __uint_as_float(v << 16);
  ay = __uint_as_float(v & 0xFFFF0000u);
  int e = start;
  for (; e + 8 <= end; e += 8) {
    unsigned w0 = Hu[(size_t)csr[e + 0] * 64 + lane];
    unsigned w1 = Hu[(size_t)csr[e + 1] * 64 + lane];
    unsigned w2 = Hu[(size_t)csr[e + 2] * 64 + lane];
    unsigned w3 = Hu[(size_t)csr[e + 3] * 64 + lane];
    unsigned w4 = Hu[(size_t)csr[e + 4] * 64 + lane];
    unsigned w5 = Hu[(size_t)csr[e + 5] * 64 + lane];
    unsigned w6 = Hu[(size_t)csr[e + 6] * 64 + lane];
    unsigned w7 = Hu[(size_t)csr[e + 7] * 64 + lane];
    ax += __uint_as_float(w0 << 16) + __uint_as_float(w1 << 16) +
          __uint_as_float(w2 << 16) + __uint_as_float(w3 << 16) +
          __uint_as_float(w4 << 16) + __uint_as_float(w5 << 16) +
          __uint_as_float(w6 << 16) + __uint_as_float(w7 << 16);
    ay += __uint_as_float(w0 & 0xFFFF0000u) + __uint_as_float(w1 & 0xFFFF0000u) +
          __uint_as_float(w2 & 0xFFFF0000u) + __uint_as_float(w3 & 0xFFFF0000u) +
          __uint_as_float(w4 & 0xFFFF0000u) + __uint_as_float(w5 & 0xFFFF0000u) +
          __uint_as_float(w6 & 0xFFFF0000u) + __uint_as_float(w7 & 0xFFFF0000u);
  }
  for (; e < end; ++e) {
    unsigned w = Hu[(size_t)csr[e] * 64 + lane];
    ax += __uint_as_float(w << 16);
    ay += __uint_as_float(w & 0xFFFF0000u);
  }
}

// ---------------- standalone gather (final layer / fallback) ----------------

__global__ __launch_bounds__(256) void gather_kernel(const int* __restrict__ csr,
                                                     const int* __restrict__ rend,
                                                     const float* __restrict__ dinv,
                                                     const unsigned* __restrict__ Hu,
                                                     const float* __restrict__ bias,
                                                     const float* __restrict__ perturb,
                                                     float* __restrict__ out, int n) {
  int i = (blockIdx.x << 2) + (threadIdx.x >> 6);
  if (i >= n) return;
  int lane = threadIdx.x & 63;
  float ax, ay;
  gather_row(csr, rend, Hu, i, lane, ax, ay);
  float di = dinv[i];
  float2 p = ((const float2*)(perturb + (size_t)i * D))[lane];
  float2 o;
  o.x = bias[2 * lane + 0] + p.x + di * ax;
  o.y = bias[2 * lane + 1] + p.y + di * ay;
  ((float2*)(out + (size_t)i * D))[lane] = o;
}

// ---------------- fused gather1 + GEMM2 (MFMA bf16) ----------------
// Block of 512 threads handles 32 nodes:
//  phase 1: 8 waves x 4 nodes gather -> out1 rows (fp32) -> bf16 LDS tile T[32][128]
//  phase 2: H2s[i] = dinv[i] * (T @ W2^T) via mfma_f32_16x16x32_bf16
// LDS pitch 136 bf16 keeps ds_read_b128 at 2-way bank aliasing (free).

#define GG_PITCH 136

__global__ __launch_bounds__(512) void gather_gemm_kernel(
    const int* __restrict__ csr, const int* __restrict__ rend,
    const float* __restrict__ dinv, const unsigned* __restrict__ Hu,
    const float* __restrict__ bias, const float* __restrict__ perturb,
    const float* __restrict__ W2, unsigned short* __restrict__ H2, int n) {
  __shared__ unsigned short W2s[128 * GG_PITCH];  // 34 KB
  __shared__ unsigned short Ts[32 * GG_PITCH];    // 8.5 KB
  const int tid = threadIdx.x;

  // stage W2 -> bf16 LDS (row-major, pitch 136)
  for (int t = tid; t < 128 * 32; t += 512) {  // 32 float4 per row
    int r = t >> 5;
    int c4 = (t & 31) << 2;
    float4 w = ((const float4*)W2)[t];
    unsigned short* p = &W2s[r * GG_PITCH + c4];
    p[0] = f2bf(w.x); p[1] = f2bf(w.y); p[2] = f2bf(w.z); p[3] = f2bf(w.w);
  }

  const int wv = tid >> 6;
  const int lane = tid & 63;
  const int base = blockIdx.x << 5;  // 32 nodes per block

  // phase 1: gather 4 nodes per wave -> Ts
  #pragma unroll
  for (int j = 0; j < 4; ++j) {
    int row = (wv << 2) + j;
    int i = base + row;
    if (i < n) {
      float ax, ay;
      gather_row(csr, rend, Hu, i, lane, ax, ay);
      float di = dinv[i];
      float2 p = ((const float2*)(perturb + (size_t)i * D))[lane];
      float ox = bias[2 * lane + 0] + p.x + di * ax;
      float oy = bias[2 * lane + 1] + p.y + di * ay;
      unsigned pack = (unsigned)f2bf(ox) | ((unsigned)f2bf(oy) << 16);
      *(unsigned*)&Ts[row * GG_PITCH + (lane << 1)] = pack;
    }
  }
  __syncthreads();

  // phase 2: R[32][128] = Ts @ W2s^T ; wave wv: m-tile = wv>>2, n-tiles {wv&3, (wv&3)+4}
  const int mt = wv >> 2;
  const int nt0 = wv & 3;
  const int m = lane & 15;
  const int quad = lane >> 4;  // 0..3
  f32x4 acc0 = {0.f, 0.f, 0.f, 0.f};
  f32x4 acc1 = {0.f, 0.f, 0.f, 0.f};
  #pragma unroll
  for (int s = 0; s < 4; ++s) {
    int k = (s << 5) + (quad << 3);
    bf16x8 a  = *(const bf16x8*)&Ts[(mt * 16 + m) * GG_PITCH + k];
    bf16x8 b0 = *(const bf16x8*)&W2s[(nt0 * 16 + m) * GG_PITCH + k];
    bf16x8 b1 = *(const bf16x8*)&W2s[((nt0 + 4) * 16 + m) * GG_PITCH + k];
    acc0 = __builtin_amdgcn_mfma_f32_16x16x32_bf16(a, b0, acc0, 0, 0, 0);
    acc1 = __builtin_amdgcn_mfma_f32_16x16x32_bf16(a, b1, acc1, 0, 0, 0);
  }
  // C/D layout: col = lane&15, row = quad*4 + reg
  #pragma unroll
  for (int r = 0; r < 4; ++r) {
    int row = mt * 16 + (quad << 2) + r;
    int g = base + row;
    if (g < n) {
      float s = dinv[g];
      H2[(size_t)g * D + nt0 * 16 + m]       = f2bf(s * acc0[r]);
      H2[(size_t)g * D + (nt0 + 4) * 16 + m] = f2bf(s * acc1[r]);
    }
  }
}

// ---------------- launch ----------------

extern "C" void kernel_launch(void* const* d_in, const int* in_sizes, int n_in,
                              void* d_out, int out_size, void* d_ws, size_t ws_size,
                              hipStream_t stream) {
  const float* x  = (const float*)d_in[0];
  const int*   ei = (const int*)d_in[1];
  const float* pf = (const float*)d_in[2];
  const float* pl = (const float*)d_in[3];
  const float* W1 = (const float*)d_in[4];
  const float* b1 = (const float*)d_in[5];
  const float* W2 = (const float*)d_in[6];
  const float* b2 = (const float*)d_in[7];
  float* out = (float*)d_out;

  const int n = in_sizes[0] / D;
  const int E = in_sizes[1] / 2;
  const int* src = ei;      // edge_index[0]
  const int* dst = ei + E;  // edge_index[1]

  // workspace layout
  int*   deg       = (int*)d_ws;                 // [n]
  float* dinv      = (float*)d_ws + n;           // [n]
  int*   ptr       = (int*)d_ws + 2 * n;         // [n] (becomes row_end after fill)
  int*   blockSums = (int*)d_ws + 3 * n;         // [<=512]
  int*   csr       = (int*)d_ws + 3 * n + 512;   // [E]
  size_t a1_off = ((size_t)(3 * n + 512 + E) * 4 + 255) & ~(size_t)255;
  unsigned short* A1 = (unsigned short*)((char*)d_ws + a1_off);
  unsigned short* A2 = A1 + (size_t)n * D;
  size_t needed = a1_off + 2 * (size_t)n * D * sizeof(unsigned short);
  const bool fused_l2 = (ws_size >= needed);  // constant across calls -> capture-safe

  const int nb_n = (n + 255) / 256;
  const int nb_e = (E + 255) / 256;
  const int nb_g = (n + 3) / 4;

  hipMemsetAsync(deg, 0, (size_t)n * sizeof(int), stream);
  count_deg_kernel<<<nb_e, 256, 0, stream>>>(dst, E, deg);
  scan_blocksum_kernel<<<nb_n, 256, 0, stream>>>(deg, n, blockSums);
  scan_top_kernel<<<1, 512, 0, stream>>>(blockSums, nb_n);
  scan_write_kernel<<<nb_n, 256, 0, stream>>>(deg, n, blockSums, ptr, dinv);

  // layer 1: CSR fill || Hs1 = dinv*(x@W1^T) -> A1
  fused_fill_gemm_kernel<<<FUSED_GRID, 256, 0, stream>>>(src, dst, ptr, csr, E, x, W1, dinv, A1, n);

  if (fused_l2) {
    // gather1 + GEMM2 fused -> A2 ; gather2 -> out
    gather_gemm_kernel<<<(n + 31) / 32, 512, 0, stream>>>(csr, ptr, dinv, (const unsigned*)A1,
                                                          b1, pf, W2, A2, n);
    gather_kernel<<<nb_g, 256, 0, stream>>>(csr, ptr, dinv, (const unsigned*)A2, b2, pl, out, n);
  } else {
    // fallback (round-3 path): gather1 -> out ; gemm2 -> A1 ; gather2 -> out
    gather_kernel<<<nb_g, 256, 0, stream>>>(csr, ptr, dinv, (const unsigned*)A1, b1, pf, out, n);
    gemm128_kernel<<<1024, 256, 0, stream>>>(out, W2, dinv, A1, n);
    gather_kernel<<<nb_g, 256, 0, stream>>>(csr, ptr, dinv, (const unsigned*)A1, b2, pl, out, n);
  }
}